// Round 9
// baseline (340.014 us; speedup 1.0000x reference)
//
#include <hip/hip_runtime.h>
#include <hip/hip_bf16.h>
#include <stdint.h>

// ---------------- constants ----------------
constexpr int Nn = 8192;
constexpr int Dd = 1024;
constexpr float kAlpha = 0.1f;
constexpr float kEps = 1e-7f;
constexpr float kInf = 3.0e38f;

constexpr int BM = 128, BN = 128;
constexpr int NB = Nn / BM;               // 64 row/col blocks
constexpr int NPAIR = NB * (NB + 1) / 2;  // 2080 upper-triangle tile pairs
constexpr int SS = Dd / 64;               // 16 K-super-steps (64 wide each)

using bfx8 = __attribute__((ext_vector_type(8))) __bf16;   // MFMA A/B frag (4 VGPRs)
using f32x4 = __attribute__((ext_vector_type(4))) float;   // MFMA C/D frag

__device__ __forceinline__ unsigned short f2bf(float f) {
  union { float f; unsigned int u; } v; v.f = f;
  unsigned int u = v.u;
  u = u + 0x7fffu + ((u >> 16) & 1u);  // RNE
  return (unsigned short)(u >> 16);
}

__device__ __forceinline__ void min2_insert(float& m1, float& m2, float x) {
  const float lo = fminf(m1, x);
  const float hi = fmaxf(m1, x);
  m1 = lo;
  m2 = fminf(m2, hi);
}

__device__ __forceinline__ void min2_merge(float& m1, float& m2, float o1, float o2) {
  m2 = fminf(fminf(m2, o2), fmaxf(m1, o1));
  m1 = fminf(m1, o1);
}

// ---------------- prep: fp32 -> bf16 + row sq-norms ----------------
__global__ __launch_bounds__(256) void prep_kernel(const float* __restrict__ H,
                                                   unsigned short* __restrict__ Hb,
                                                   float* __restrict__ xn) {
  const int wave = threadIdx.x >> 6;
  const int lane = threadIdx.x & 63;
  const int row = blockIdx.x * 4 + wave;
  const float4* src = (const float4*)(H + (size_t)row * Dd);
  ushort4* dst = (ushort4*)(Hb + (size_t)row * Dd);
  float acc = 0.f;
#pragma unroll
  for (int i = 0; i < 4; ++i) {
    float4 v = src[lane + 64 * i];
    acc = fmaf(v.x, v.x, acc);
    acc = fmaf(v.y, v.y, acc);
    acc = fmaf(v.z, v.z, acc);
    acc = fmaf(v.w, v.w, acc);
    ushort4 o;
    o.x = f2bf(v.x); o.y = f2bf(v.y); o.z = f2bf(v.z); o.w = f2bf(v.w);
    dst[lane + 64 * i] = o;
  }
#pragma unroll
  for (int off = 32; off; off >>= 1) acc += __shfl_xor(acc, off, 64);
  if (lane == 0) xn[row] = acc;
}

// ---------------- main: SYNC-FREE register-streaming GEMM + reductions -------
// grid = 2080 upper-triangle pairs (I<=J), 4 waves/block, wave tile 64x64.
//
// Session evidence (r0-r8): every LDS-staged schedule (drain/counted-vmcnt/
// 8-phase/2-step cadence) lands at 122-186us with no pipe saturated — the
// invariant is the staging+barrier dependency chain. This version removes it:
// MFMA fragments for 16x16x32 are row-major-aligned 16B global loads
// (lane(l15,quad) reads Hb[row][kt+quad*8..+8)), so A and B stream
// global->VGPR directly. NO LDS, NO barriers in the K-loop. K in super-steps
// of 64: 16 dwordx4 loads/wave (both 64B halves of each row's 128B line ->
// zero sector waste), double-banked X/Y so bank s+1 loads issue before bank
// s's 32 MFMAs; the compiler emits exact counted vmcnt waits on register
// deps. A-rows shared by 2 waves/CU -> L1 absorbs duplication.
// Regs ~ 64 acc + 128 banks + 16 ptrs -> launch_bounds(256,2), 2 blocks/CU.
__global__ __launch_bounds__(256, 2) void triplet_main(
    const unsigned short* __restrict__ Hb, const float* __restrict__ xn,
    const int* __restrict__ lab, float* __restrict__ wsMax,
    float* __restrict__ wsM1, float* __restrict__ wsM2) {
  const int tid = threadIdx.x;
  const int wave = tid >> 6;
  const int lane = tid & 63;
  const int quad = lane >> 4;
  const int l15 = lane & 15;
  const int wm = wave & 1;
  const int wn = wave >> 1;

  // XCD-aware swizzle: 8 XCDs, contiguous chunk of 260 pairs per XCD.
  int bid = (int)blockIdx.x;
  bid = (bid & 7) * (NPAIR / 8) + (bid >> 3);

  // decode pair index -> (I, J), I <= J
  int b = bid, I = 0;
  while (b >= NB - I) { b -= NB - I; ++I; }
  const int J = I + b;
  const bool diag = (I == J);

  const int rowBase = I * BM;
  const int colBase = J * BN;

  f32x4 acc[4][4];
#pragma unroll
  for (int m = 0; m < 4; ++m)
#pragma unroll
    for (int n = 0; n < 4; ++n) acc[m][n] = {0.f, 0.f, 0.f, 0.f};

  // per-frag row base pointers (advance 128 shorts = 2 super-steps after use)
  const unsigned short* pA[4];
  const unsigned short* pB[4];
#pragma unroll
  for (int m = 0; m < 4; ++m)
    pA[m] = Hb + (size_t)(rowBase + wm * 64 + m * 16 + l15) * Dd + quad * 8;
#pragma unroll
  for (int n = 0; n < 4; ++n)
    pB[n] = Hb + (size_t)(colBase + wn * 64 + n * 16 + l15) * Dd + quad * 8;

  bfx8 aX[4][2], bX[4][2], aY[4][2], bY[4][2];

  // bank X <- super-step 0 (k = 0..63)
#pragma unroll
  for (int m = 0; m < 4; ++m) {
    aX[m][0] = *(const bfx8*)(pA[m]);
    aX[m][1] = *(const bfx8*)(pA[m] + 32);
    bX[m][0] = *(const bfx8*)(pB[m]);
    bX[m][1] = *(const bfx8*)(pB[m] + 32);
  }

  for (int s = 0; s < SS; s += 2) {
    // issue bank Y loads (super-step s+1, k = s*64+64) — SS is even, always valid
#pragma unroll
    for (int m = 0; m < 4; ++m) {
      aY[m][0] = *(const bfx8*)(pA[m] + 64);
      aY[m][1] = *(const bfx8*)(pA[m] + 96);
      bY[m][0] = *(const bfx8*)(pB[m] + 64);
      bY[m][1] = *(const bfx8*)(pB[m] + 96);
    }
    // consume bank X (32 MFMAs; compiler waits on X regs only)
#pragma unroll
    for (int sl = 0; sl < 2; ++sl)
#pragma unroll
      for (int m = 0; m < 4; ++m)
#pragma unroll
        for (int n = 0; n < 4; ++n)
          acc[m][n] = __builtin_amdgcn_mfma_f32_16x16x32_bf16(aX[m][sl], bX[n][sl],
                                                              acc[m][n], 0, 0, 0);
    // advance pointers past the two super-steps being processed
#pragma unroll
    for (int m = 0; m < 4; ++m) { pA[m] += 128; pB[m] += 128; }
    // issue bank X loads (super-step s+2) — skip on last pair
    if (s + 2 < SS) {
#pragma unroll
      for (int m = 0; m < 4; ++m) {
        aX[m][0] = *(const bfx8*)(pA[m]);
        aX[m][1] = *(const bfx8*)(pA[m] + 32);
        bX[m][0] = *(const bfx8*)(pB[m]);
        bX[m][1] = *(const bfx8*)(pB[m] + 32);
      }
    }
    // consume bank Y
#pragma unroll
    for (int sl = 0; sl < 2; ++sl)
#pragma unroll
      for (int m = 0; m < 4; ++m)
#pragma unroll
        for (int n = 0; n < 4; ++n)
          acc[m][n] = __builtin_amdgcn_mfma_f32_16x16x32_bf16(aY[m][sl], bY[n][sl],
                                                              acc[m][n], 0, 0, 0);
  }

  // ---- epilogue: dist = xr + xc - 2*G; both-sided masked reductions ----
  float maxp[16], mn1[16], mn2[16];
#pragma unroll
  for (int s = 0; s < 16; ++s) { maxp[s] = 0.f; mn1[s] = kInf; mn2[s] = kInf; }

  int lr[16]; float xr[16];
#pragma unroll
  for (int m = 0; m < 4; ++m)
#pragma unroll
    for (int r = 0; r < 4; ++r) {
      const int row = rowBase + wm * 64 + m * 16 + quad * 4 + r;
      lr[m * 4 + r] = lab[row];
      xr[m * 4 + r] = xn[row];
    }
  int lc[4]; float xc[4];
#pragma unroll
  for (int n = 0; n < 4; ++n) {
    const int col = colBase + wn * 64 + n * 16 + l15;
    lc[n] = lab[col];
    xc[n] = xn[col];
  }
  float tmaxp[4], tmn1[4], tmn2[4];
#pragma unroll
  for (int n = 0; n < 4; ++n) { tmaxp[n] = 0.f; tmn1[n] = kInf; tmn2[n] = kInf; }

  if (!diag) {
#pragma unroll
    for (int m = 0; m < 4; ++m)
#pragma unroll
      for (int n = 0; n < 4; ++n)
#pragma unroll
        for (int r = 0; r < 4; ++r) {
          const int s = m * 4 + r;
          const float d = fmaf(-2.f, acc[m][n][r], xr[s] + xc[n]);
          const bool eq = (lr[s] == lc[n]);
          const float pos = eq ? d : 0.f;
          const float dn = eq ? kInf : d;
          maxp[s] = fmaxf(maxp[s], pos);
          min2_insert(mn1[s], mn2[s], dn);
          tmaxp[n] = fmaxf(tmaxp[n], pos);
          min2_insert(tmn1[n], tmn2[n], dn);
        }
  } else {
#pragma unroll
    for (int m = 0; m < 4; ++m)
#pragma unroll
      for (int n = 0; n < 4; ++n)
#pragma unroll
        for (int r = 0; r < 4; ++r) {
          const int s = m * 4 + r;
          // self-pair only possible on the diagonal tile
          const bool selfp = (wm == wn) && (m == n) && (quad * 4 + r == l15);
          const float d = fmaf(-2.f, acc[m][n][r], xr[s] + xc[n]);
          const bool eq = (lr[s] == lc[n]);
          const float pos = (eq && !selfp) ? d : 0.f;
          const float dn = eq ? kInf : d;  // self is eq -> excluded from negatives
          maxp[s] = fmaxf(maxp[s], pos);
          min2_insert(mn1[s], mn2[s], dn);
        }
  }

  // cross-lane row merge over the 16 column-lanes
#pragma unroll
  for (int off = 1; off < 16; off <<= 1) {
#pragma unroll
    for (int s = 0; s < 16; ++s) {
      const float om = __shfl_xor(maxp[s], off, 64);
      const float o1 = __shfl_xor(mn1[s], off, 64);
      const float o2 = __shfl_xor(mn2[s], off, 64);
      maxp[s] = fmaxf(maxp[s], om);
      min2_merge(mn1[s], mn2[s], o1, o2);
    }
  }

  // ---- LDS scratch phase (small epilogue-only scratch; first barrier also
  // collects the free-running waves) ----
  __shared__ __align__(16) float smem_f[3456];  // 13.5 KB
  float* rbuf = smem_f;           // [2(wm)][64(local)][3]   = 384 floats
  float* tbm = smem_f + 384;      // [2(wm)][2(wn)][4(q)][4(n)][16(l15)] = 1024 each
  float* tb1 = tbm + 1024;
  float* tb2 = tb1 + 1024;

  if (wn == 1 && l15 == 0) {
#pragma unroll
    for (int m = 0; m < 4; ++m)
#pragma unroll
      for (int r = 0; r < 4; ++r) {
        const int s = m * 4 + r;
        const int local = m * 16 + quad * 4 + r;
        rbuf[(wm * 64 + local) * 3 + 0] = maxp[s];
        rbuf[(wm * 64 + local) * 3 + 1] = mn1[s];
        rbuf[(wm * 64 + local) * 3 + 2] = mn2[s];
      }
  }
#pragma unroll
  for (int n = 0; n < 4; ++n) {
    const int idx = (((wm * 2 + wn) * 4 + quad) * 4 + n) * 16 + l15;
    tbm[idx] = tmaxp[n];
    tb1[idx] = tmn1[n];
    tb2[idx] = tmn2[n];
  }
  __syncthreads();

  // row side: wn==0 waves merge rbuf and write P[I][J]
  if (wn == 0 && l15 == 0) {
#pragma unroll
    for (int m = 0; m < 4; ++m)
#pragma unroll
      for (int r = 0; r < 4; ++r) {
        const int s = m * 4 + r;
        const int local = m * 16 + quad * 4 + r;
        float om = rbuf[(wm * 64 + local) * 3 + 0];
        float o1 = rbuf[(wm * 64 + local) * 3 + 1];
        float o2 = rbuf[(wm * 64 + local) * 3 + 2];
        const float M = fmaxf(maxp[s], om);
        float a1 = mn1[s], a2 = mn2[s];
        min2_merge(a1, a2, o1, o2);
        const size_t p = ((size_t)(I * NB + J)) * 128 + wm * 64 + local;
        wsMax[p] = M;
        wsM1[p] = a1;
        wsM2[p] = a2;
      }
  }
  // transposed side: wm==0 waves merge tbuf over {wm2, quad} and write P[J][I]
  if (wm == 0 && !diag) {
    const int tn = lane >> 4;
    const int tl = lane & 15;
    float M = 0.f, a1 = kInf, a2 = kInf;
#pragma unroll
    for (int wm2 = 0; wm2 < 2; ++wm2)
#pragma unroll
      for (int q = 0; q < 4; ++q) {
        const int idx = (((wm2 * 2 + wn) * 4 + q) * 4 + tn) * 16 + tl;
        M = fmaxf(M, tbm[idx]);
        min2_merge(a1, a2, tb1[idx], tb2[idx]);
      }
    const size_t p = ((size_t)(J * NB + I)) * 128 + wn * 64 + lane;
    wsMax[p] = M;
    wsM1[p] = a1;
    wsM2[p] = a2;
  }
}

// ---------------- merge: per-row over 64 col-block partials -> block sums ----
// 256 threads: row = tid&127, half = tid>>7 covers 32 of the 64 bj each;
// halves merged through LDS, loss computed on half 0.
__global__ __launch_bounds__(256) void merge_kernel(
    const float* __restrict__ wsMax, const float* __restrict__ wsM1,
    const float* __restrict__ wsM2, float* __restrict__ bsum,
    float* __restrict__ bcnt) {
  const int r = threadIdx.x & 127;
  const int h = threadIdx.x >> 7;
  const int bi = blockIdx.x;
  float mp = 0.f, m1 = kInf, m2 = kInf;
#pragma unroll 8
  for (int bj = h * 32; bj < h * 32 + 32; ++bj) {
    const size_t p = ((size_t)(bi * NB + bj)) * 128 + r;
    mp = fmaxf(mp, wsMax[p]);
    min2_merge(m1, m2, wsM1[p], wsM2[p]);
  }
  __shared__ float hmax[128], hm1[128], hm2[128];
  if (h == 1) { hmax[r] = mp; hm1[r] = m1; hm2[r] = m2; }
  __syncthreads();
  float ls = 0.f, lc = 0.f;
  if (h == 0) {
    mp = fmaxf(mp, hmax[r]);
    min2_merge(m1, m2, hm1[r], hm2[r]);
    const float loss = fmaxf(mp - m2 + kAlpha, 0.f);
    ls = (loss > kEps) ? loss : 0.f;
    lc = (loss > kEps) ? 1.f : 0.f;
  }
#pragma unroll
  for (int off = 32; off; off >>= 1) {
    ls += __shfl_down(ls, off, 64);
    lc += __shfl_down(lc, off, 64);
  }
  __shared__ float ss[2], sc[2];
  if (h == 0 && (threadIdx.x & 63) == 0) {
    ss[threadIdx.x >> 6] = ls;
    sc[threadIdx.x >> 6] = lc;
  }
  __syncthreads();
  if (threadIdx.x == 0) {
    bsum[bi] = ss[0] + ss[1];
    bcnt[bi] = sc[0] + sc[1];
  }
}

// ---------------- final: reduce 64 block sums, divide ----------------
__global__ __launch_bounds__(64) void final_kernel(const float* __restrict__ bsum,
                                                   const float* __restrict__ bcnt,
                                                   float* __restrict__ out) {
  float s = bsum[threadIdx.x];
  float c = bcnt[threadIdx.x];
#pragma unroll
  for (int off = 32; off; off >>= 1) {
    s += __shfl_down(s, off, 64);
    c += __shfl_down(c, off, 64);
  }
  if (threadIdx.x == 0) out[0] = s / c;
}

// ---------------- launch ----------------
extern "C" void kernel_launch(void* const* d_in, const int* in_sizes, int n_in,
                              void* d_out, int out_size, void* d_ws, size_t ws_size,
                              hipStream_t stream) {
  (void)in_sizes; (void)n_in; (void)out_size; (void)ws_size;
  const float* H = (const float*)d_in[0];
  const int* lab = (const int*)d_in[1];
  float* out = (float*)d_out;

  char* ws = (char*)d_ws;
  unsigned short* Hb = (unsigned short*)ws;                              // 16 MB
  float* xn = (float*)(ws + (size_t)Nn * Dd * sizeof(unsigned short));   // 32 KB
  float* wsMax = xn + Nn;                 // 64*64*128 = 512K floats = 2 MB
  float* wsM1 = wsMax + NB * NB * 128;
  float* wsM2 = wsM1 + NB * NB * 128;
  float* bsum = wsM2 + NB * NB * 128;     // 64 floats
  float* bcnt = bsum + NB;

  prep_kernel<<<Nn / 4, 256, 0, stream>>>(H, Hb, xn);
  triplet_main<<<NPAIR, 256, 0, stream>>>(Hb, xn, lab, wsMax, wsM1, wsM2);
  merge_kernel<<<NB, 256, 0, stream>>>(wsMax, wsM1, wsM2, bsum, bcnt);
  final_kernel<<<1, 64, 0, stream>>>(bsum, bcnt, out);
}

// Round 10
// 183.453 us; speedup vs baseline: 1.8534x; 1.8534x over previous
//
#include <hip/hip_runtime.h>
#include <hip/hip_bf16.h>
#include <stdint.h>

// ---------------- constants ----------------
constexpr int Nn = 8192;
constexpr int Dd = 1024;
constexpr float kAlpha = 0.1f;
constexpr float kEps = 1e-7f;
constexpr float kInf = 3.0e38f;

constexpr int BM = 128, BN = 128, BK = 32;
constexpr int NB = Nn / BM;               // 64 row/col blocks
constexpr int NPAIR = NB * (NB + 1) / 2;  // 2080 upper-triangle tile pairs

// Hb is stored K-TILED: [rowBlk 64][kt 32][row 128][k 32] — each 128x32 tile
// is a contiguous 8 KB blob (4096 shorts). Offset(row,k) =
//   ((row>>7)*32 + (k>>5))*4096 + (row&127)*32 + (k&31)
constexpr int TILE_SH = 4096;             // shorts per 8 KB tile

using bfx8 = __attribute__((ext_vector_type(8))) __bf16;   // MFMA A/B frag (4 VGPRs)
using f32x4 = __attribute__((ext_vector_type(4))) float;   // MFMA C/D frag

__device__ __forceinline__ unsigned short f2bf(float f) {
  union { float f; unsigned int u; } v; v.f = f;
  unsigned int u = v.u;
  u = u + 0x7fffu + ((u >> 16) & 1u);  // RNE
  return (unsigned short)(u >> 16);
}

__device__ __forceinline__ void min2_insert(float& m1, float& m2, float x) {
  const float lo = fminf(m1, x);
  const float hi = fmaxf(m1, x);
  m1 = lo;
  m2 = fminf(m2, hi);
}

__device__ __forceinline__ void min2_merge(float& m1, float& m2, float o1, float o2) {
  m2 = fminf(fminf(m2, o2), fmaxf(m1, o1));
  m1 = fminf(m1, o1);
}

// ---------------- prep: fp32 -> bf16 (K-tiled layout) + row sq-norms --------
__global__ __launch_bounds__(256) void prep_kernel(const float* __restrict__ H,
                                                   unsigned short* __restrict__ Hb,
                                                   float* __restrict__ xn) {
  const int wave = threadIdx.x >> 6;
  const int lane = threadIdx.x & 63;
  const int row = blockIdx.x * 4 + wave;
  const float4* src = (const float4*)(H + (size_t)row * Dd);
  // K-tiled destination: tile (row>>7, k>>5), element (row&127, k&31)
  unsigned short* dstBase =
      Hb + ((size_t)(row >> 7) * 32) * TILE_SH + (row & 127) * 32;
  float acc = 0.f;
#pragma unroll
  for (int i = 0; i < 4; ++i) {
    float4 v = src[lane + 64 * i];
    acc = fmaf(v.x, v.x, acc);
    acc = fmaf(v.y, v.y, acc);
    acc = fmaf(v.z, v.z, acc);
    acc = fmaf(v.w, v.w, acc);
    ushort4 o;
    o.x = f2bf(v.x); o.y = f2bf(v.y); o.z = f2bf(v.z); o.w = f2bf(v.w);
    const int k4 = (lane + 64 * i) * 4;  // first k of this ushort4
    *(ushort4*)(dstBase + (k4 >> 5) * TILE_SH + (k4 & 31)) = o;
  }
#pragma unroll
  for (int off = 32; off; off >>= 1) acc += __shfl_xor(acc, off, 64);
  if (lane == 0) xn[row] = acc;
}

// ---------------- main: symmetric fused GEMM + triplet reductions ----------------
// grid = 2080 upper-triangle pairs (I<=J). EXACT r1 structure (best measured:
// 122.6us) — double-buffered LDS prefetch, one barrier per K-step, both-sides
// XOR swizzle, XCD-aware bid swizzle, (256,3).
// ONLY change this round: Hb is K-tiled, so every global_load_lds reads a
// fully CONTIGUOUS 1 KB (8 full 128B lines) instead of 16 scattered 64B
// half-lines — L2 request count halves, all requests full-line. The 16B XOR
// swizzle is a permutation within each row's 64B group (source-side; LDS dest
// stays linear), so LDS contents are bit-identical to r1.
__global__ __launch_bounds__(256, 3) void triplet_main(
    const unsigned short* __restrict__ Hb, const float* __restrict__ xn,
    const int* __restrict__ lab, float* __restrict__ wsMax,
    float* __restrict__ wsM1, float* __restrict__ wsM2) {
  __shared__ __align__(16) unsigned char smem[32768];  // 2 x (8KB A + 8KB B)

  const int tid = threadIdx.x;
  const int wave = tid >> 6;
  const int lane = tid & 63;
  const int quad = lane >> 4;
  const int l15 = lane & 15;
  const int wm = wave & 1;
  const int wn = wave >> 1;

  // XCD-aware swizzle: 8 XCDs, contiguous chunk of 260 pairs per XCD.
  int bid = (int)blockIdx.x;
  bid = (bid & 7) * (NPAIR / 8) + (bid >> 3);

  // decode pair index -> (I, J), I <= J
  int b = bid, I = 0;
  while (b >= NB - I) { b -= NB - I; ++I; }
  const int J = I + b;
  const bool diag = (I == J);

  const int rowBase = I * BM;
  const int colBase = J * BN;

  // per-lane row metadata: slot s = m*4+r -> row = rowBase + wm*64 + m*16 + quad*4 + r
  int lr[16]; float xr[16];
#pragma unroll
  for (int m = 0; m < 4; ++m)
#pragma unroll
    for (int r = 0; r < 4; ++r) {
      const int row = rowBase + wm * 64 + m * 16 + quad * 4 + r;
      lr[m * 4 + r] = lab[row];
      xr[m * 4 + r] = xn[row];
    }

  float maxp[16], mn1[16], mn2[16];
#pragma unroll
  for (int s = 0; s < 16; ++s) { maxp[s] = 0.f; mn1[s] = kInf; mn2[s] = kInf; }

  // staging map: wave stages rows [wave*32 + j*16, +16); lane -> (row, 16B slot)
  // slot is XOR-swizzled within the 64B row: physical slot p holds logical
  // slot p ^ ((localRow>>1)&3); applied on the K-tiled GLOBAL source (a
  // within-64B permutation), LDS dest stays linear.
  const int stR = lane >> 2;                                  // local row 0..15
  const int stRow = wave * 32 + stR;                          // tile row (j adds 16)
  const int stCol = ((lane & 3) ^ ((stR >> 1) & 3)) * 8;      // swizzled short off
  // read-side swizzle: same XOR keyed by the local row (= l15 for frag reads)
  const int swq = quad ^ ((l15 >> 1) & 3);

  f32x4 acc[4][4];
#pragma unroll
  for (int m = 0; m < 4; ++m)
#pragma unroll
    for (int n = 0; n < 4; ++n) acc[m][n] = {0.f, 0.f, 0.f, 0.f};

  auto stage = [&](int bsel, int kti) {  // kti = K-tile index (k/32)
    unsigned short* As = (unsigned short*)(smem + bsel * 16384);
    unsigned short* Bs = (unsigned short*)(smem + bsel * 16384 + 8192);
    const unsigned short* baseA = Hb + (size_t)(I * 32 + kti) * TILE_SH;
    const unsigned short* baseB = Hb + (size_t)(J * 32 + kti) * TILE_SH;
#pragma unroll
    for (int j = 0; j < 2; ++j) {
      const unsigned short* ga = baseA + (stRow + j * 16) * 32 + stCol;
      __builtin_amdgcn_global_load_lds(
          (const __attribute__((address_space(1))) void*)ga,
          (__attribute__((address_space(3))) void*)&As[(wave * 2 + j) * 512],
          16, 0, 0);
      const unsigned short* gb = baseB + (stRow + j * 16) * 32 + stCol;
      __builtin_amdgcn_global_load_lds(
          (const __attribute__((address_space(1))) void*)gb,
          (__attribute__((address_space(3))) void*)&Bs[(wave * 2 + j) * 512],
          16, 0, 0);
    }
  };

  // prologue: stage tile 0 into buffer 0, drain, then pipeline.
  stage(0, 0);
  __syncthreads();  // drains vmcnt (global_load_lds) + lgkm

  int cur = 0;
  for (int kti = 0; kti < Dd / BK; ++kti) {
    if (kti + 1 < Dd / BK) stage(cur ^ 1, kti + 1);  // prefetch next (issue only)

    const unsigned short* As = (const unsigned short*)(smem + cur * 16384);
    const unsigned short* Bs = (const unsigned short*)(smem + cur * 16384 + 8192);
    bfx8 a[4], bb[4];
#pragma unroll
    for (int m = 0; m < 4; ++m)
      a[m] = *(const bfx8*)&As[(wm * 64 + m * 16 + l15) * BK + swq * 8];
#pragma unroll
    for (int n = 0; n < 4; ++n)
      bb[n] = *(const bfx8*)&Bs[(wn * 64 + n * 16 + l15) * BK + swq * 8];
#pragma unroll
    for (int m = 0; m < 4; ++m)
#pragma unroll
      for (int n = 0; n < 4; ++n)
        acc[m][n] = __builtin_amdgcn_mfma_f32_16x16x32_bf16(a[m], bb[n], acc[m][n], 0, 0, 0);

    __syncthreads();  // one drain+barrier per K-step; prefetch had compute cover
    cur ^= 1;
  }

  // ---- epilogue: dist = xr + xc - 2*G; both-sided masked reductions ----
  int lc[4]; float xc[4];
#pragma unroll
  for (int n = 0; n < 4; ++n) {
    const int col = colBase + wn * 64 + n * 16 + l15;
    lc[n] = lab[col];
    xc[n] = xn[col];
  }
  float tmaxp[4], tmn1[4], tmn2[4];
#pragma unroll
  for (int n = 0; n < 4; ++n) { tmaxp[n] = 0.f; tmn1[n] = kInf; tmn2[n] = kInf; }

  if (!diag) {
#pragma unroll
    for (int m = 0; m < 4; ++m)
#pragma unroll
      for (int n = 0; n < 4; ++n)
#pragma unroll
        for (int r = 0; r < 4; ++r) {
          const int s = m * 4 + r;
          const float d = fmaf(-2.f, acc[m][n][r], xr[s] + xc[n]);
          const bool eq = (lr[s] == lc[n]);
          const float pos = eq ? d : 0.f;
          const float dn = eq ? kInf : d;
          maxp[s] = fmaxf(maxp[s], pos);
          min2_insert(mn1[s], mn2[s], dn);
          tmaxp[n] = fmaxf(tmaxp[n], pos);
          min2_insert(tmn1[n], tmn2[n], dn);
        }
  } else {
#pragma unroll
    for (int m = 0; m < 4; ++m)
#pragma unroll
      for (int n = 0; n < 4; ++n)
#pragma unroll
        for (int r = 0; r < 4; ++r) {
          const int s = m * 4 + r;
          // self-pair only possible on the diagonal tile
          const bool selfp = (wm == wn) && (m == n) && (quad * 4 + r == l15);
          const float d = fmaf(-2.f, acc[m][n][r], xr[s] + xc[n]);
          const bool eq = (lr[s] == lc[n]);
          const float pos = (eq && !selfp) ? d : 0.f;
          const float dn = eq ? kInf : d;  // self is eq -> excluded from negatives
          maxp[s] = fmaxf(maxp[s], pos);
          min2_insert(mn1[s], mn2[s], dn);
        }
  }

  // cross-lane row merge over the 16 column-lanes
#pragma unroll
  for (int off = 1; off < 16; off <<= 1) {
#pragma unroll
    for (int s = 0; s < 16; ++s) {
      const float om = __shfl_xor(maxp[s], off, 64);
      const float o1 = __shfl_xor(mn1[s], off, 64);
      const float o2 = __shfl_xor(mn2[s], off, 64);
      maxp[s] = fmaxf(maxp[s], om);
      min2_merge(mn1[s], mn2[s], o1, o2);
    }
  }

  // ---- LDS scratch phase (reuse staging buffers; loop's final barrier
  // already ordered all LDS traffic) ----
  float* rbuf = (float*)smem;        // [2(wm)][64(local)][3]   = 384 floats
  float* tbm = ((float*)smem) + 384; // [2(wm)][2(wn)][4(q)][4(n)][16(l15)] = 1024 each
  float* tb1 = tbm + 1024;
  float* tb2 = tb1 + 1024;

  if (wn == 1 && l15 == 0) {
#pragma unroll
    for (int m = 0; m < 4; ++m)
#pragma unroll
      for (int r = 0; r < 4; ++r) {
        const int s = m * 4 + r;
        const int local = m * 16 + quad * 4 + r;
        rbuf[(wm * 64 + local) * 3 + 0] = maxp[s];
        rbuf[(wm * 64 + local) * 3 + 1] = mn1[s];
        rbuf[(wm * 64 + local) * 3 + 2] = mn2[s];
      }
  }
#pragma unroll
  for (int n = 0; n < 4; ++n) {
    const int idx = (((wm * 2 + wn) * 4 + quad) * 4 + n) * 16 + l15;
    tbm[idx] = tmaxp[n];
    tb1[idx] = tmn1[n];
    tb2[idx] = tmn2[n];
  }
  __syncthreads();

  // row side: wn==0 waves merge rbuf and write P[I][J]
  if (wn == 0 && l15 == 0) {
#pragma unroll
    for (int m = 0; m < 4; ++m)
#pragma unroll
      for (int r = 0; r < 4; ++r) {
        const int s = m * 4 + r;
        const int local = m * 16 + quad * 4 + r;
        float om = rbuf[(wm * 64 + local) * 3 + 0];
        float o1 = rbuf[(wm * 64 + local) * 3 + 1];
        float o2 = rbuf[(wm * 64 + local) * 3 + 2];
        const float M = fmaxf(maxp[s], om);
        float a1 = mn1[s], a2 = mn2[s];
        min2_merge(a1, a2, o1, o2);
        const size_t p = ((size_t)(I * NB + J)) * 128 + wm * 64 + local;
        wsMax[p] = M;
        wsM1[p] = a1;
        wsM2[p] = a2;
      }
  }
  // transposed side: wm==0 waves merge tbuf over {wm2, quad} and write P[J][I]
  if (wm == 0 && !diag) {
    const int tn = lane >> 4;
    const int tl = lane & 15;
    float M = 0.f, a1 = kInf, a2 = kInf;
#pragma unroll
    for (int wm2 = 0; wm2 < 2; ++wm2)
#pragma unroll
      for (int q = 0; q < 4; ++q) {
        const int idx = (((wm2 * 2 + wn) * 4 + q) * 4 + tn) * 16 + tl;
        M = fmaxf(M, tbm[idx]);
        min2_merge(a1, a2, tb1[idx], tb2[idx]);
      }
    const size_t p = ((size_t)(J * NB + I)) * 128 + wn * 64 + lane;
    wsMax[p] = M;
    wsM1[p] = a1;
    wsM2[p] = a2;
  }
}

// ---------------- merge: per-row over 64 col-block partials -> block sums ----
// 256 threads: row = tid&127, half = tid>>7 covers 32 of the 64 bj each;
// halves merged through LDS, loss computed on half 0.
__global__ __launch_bounds__(256) void merge_kernel(
    const float* __restrict__ wsMax, const float* __restrict__ wsM1,
    const float* __restrict__ wsM2, float* __restrict__ bsum,
    float* __restrict__ bcnt) {
  const int r = threadIdx.x & 127;
  const int h = threadIdx.x >> 7;
  const int bi = blockIdx.x;
  float mp = 0.f, m1 = kInf, m2 = kInf;
#pragma unroll 8
  for (int bj = h * 32; bj < h * 32 + 32; ++bj) {
    const size_t p = ((size_t)(bi * NB + bj)) * 128 + r;
    mp = fmaxf(mp, wsMax[p]);
    min2_merge(m1, m2, wsM1[p], wsM2[p]);
  }
  __shared__ float hmax[128], hm1[128], hm2[128];
  if (h == 1) { hmax[r] = mp; hm1[r] = m1; hm2[r] = m2; }
  __syncthreads();
  float ls = 0.f, lc = 0.f;
  if (h == 0) {
    mp = fmaxf(mp, hmax[r]);
    min2_merge(m1, m2, hm1[r], hm2[r]);
    const float loss = fmaxf(mp - m2 + kAlpha, 0.f);
    ls = (loss > kEps) ? loss : 0.f;
    lc = (loss > kEps) ? 1.f : 0.f;
  }
#pragma unroll
  for (int off = 32; off; off >>= 1) {
    ls += __shfl_down(ls, off, 64);
    lc += __shfl_down(lc, off, 64);
  }
  __shared__ float ss[2], sc[2];
  if (h == 0 && (threadIdx.x & 63) == 0) {
    ss[threadIdx.x >> 6] = ls;
    sc[threadIdx.x >> 6] = lc;
  }
  __syncthreads();
  if (threadIdx.x == 0) {
    bsum[bi] = ss[0] + ss[1];
    bcnt[bi] = sc[0] + sc[1];
  }
}

// ---------------- final: reduce 64 block sums, divide ----------------
__global__ __launch_bounds__(64) void final_kernel(const float* __restrict__ bsum,
                                                   const float* __restrict__ bcnt,
                                                   float* __restrict__ out) {
  float s = bsum[threadIdx.x];
  float c = bcnt[threadIdx.x];
#pragma unroll
  for (int off = 32; off; off >>= 1) {
    s += __shfl_down(s, off, 64);
    c += __shfl_down(c, off, 64);
  }
  if (threadIdx.x == 0) out[0] = s / c;
}

// ---------------- launch ----------------
extern "C" void kernel_launch(void* const* d_in, const int* in_sizes, int n_in,
                              void* d_out, int out_size, void* d_ws, size_t ws_size,
                              hipStream_t stream) {
  (void)in_sizes; (void)n_in; (void)out_size; (void)ws_size;
  const float* H = (const float*)d_in[0];
  const int* lab = (const int*)d_in[1];
  float* out = (float*)d_out;

  char* ws = (char*)d_ws;
  unsigned short* Hb = (unsigned short*)ws;                              // 16 MB (K-tiled)
  float* xn = (float*)(ws + (size_t)Nn * Dd * sizeof(unsigned short));   // 32 KB
  float* wsMax = xn + Nn;                 // 64*64*128 = 512K floats = 2 MB
  float* wsM1 = wsMax + NB * NB * 128;
  float* wsM2 = wsM1 + NB * NB * 128;
  float* bsum = wsM2 + NB * NB * 128;     // 64 floats
  float* bcnt = bsum + NB;

  prep_kernel<<<Nn / 4, 256, 0, stream>>>(H, Hb, xn);
  triplet_main<<<NPAIR, 256, 0, stream>>>(Hb, xn, lab, wsMax, wsM1, wsM2);
  merge_kernel<<<NB, 256, 0, stream>>>(wsMax, wsM1, wsM2, bsum, bcnt);
  final_kernel<<<1, 64, 0, stream>>>(bsum, bcnt, out);
}

// Round 11
// 183.122 us; speedup vs baseline: 1.8568x; 1.0018x over previous
//
#include <hip/hip_runtime.h>
#include <hip/hip_bf16.h>
#include <stdint.h>

// ---------------- constants ----------------
constexpr int Nn = 8192;
constexpr int Dd = 1024;
constexpr float kAlpha = 0.1f;
constexpr float kEps = 1e-7f;
constexpr float kInf = 3.0e38f;

constexpr int BM = 128, BN = 128, BK = 32;
constexpr int NB = Nn / BM;               // 64 row/col blocks
constexpr int NPAIR = NB * (NB + 1) / 2;  // 2080 upper-triangle tile pairs
constexpr int NT = Dd / BK;               // 32 K-steps

// Hb is stored K-TILED: [rowBlk 64][kt 32][row 128][k 32] — each 128x32 tile
// is a contiguous 8 KB blob (4096 shorts). Offset(row,k) =
//   ((row>>7)*32 + (k>>5))*4096 + (row&127)*32 + (k&31)
constexpr int TILE_SH = 4096;             // shorts per 8 KB tile

using bfx8 = __attribute__((ext_vector_type(8))) __bf16;   // MFMA A/B frag (4 VGPRs)
using f32x4 = __attribute__((ext_vector_type(4))) float;   // MFMA C/D frag

__device__ __forceinline__ unsigned short f2bf(float f) {
  union { float f; unsigned int u; } v; v.f = f;
  unsigned int u = v.u;
  u = u + 0x7fffu + ((u >> 16) & 1u);  // RNE
  return (unsigned short)(u >> 16);
}

__device__ __forceinline__ void min2_insert(float& m1, float& m2, float x) {
  const float lo = fminf(m1, x);
  const float hi = fmaxf(m1, x);
  m1 = lo;
  m2 = fminf(m2, hi);
}

__device__ __forceinline__ void min2_merge(float& m1, float& m2, float o1, float o2) {
  m2 = fminf(fminf(m2, o2), fmaxf(m1, o1));
  m1 = fminf(m1, o1);
}

// ---------------- prep: fp32 -> bf16 (K-tiled layout) + row sq-norms --------
__global__ __launch_bounds__(256) void prep_kernel(const float* __restrict__ H,
                                                   unsigned short* __restrict__ Hb,
                                                   float* __restrict__ xn) {
  const int wave = threadIdx.x >> 6;
  const int lane = threadIdx.x & 63;
  const int row = blockIdx.x * 4 + wave;
  const float4* src = (const float4*)(H + (size_t)row * Dd);
  // K-tiled destination: tile (row>>7, k>>5), element (row&127, k&31)
  unsigned short* dstBase =
      Hb + ((size_t)(row >> 7) * 32) * TILE_SH + (row & 127) * 32;
  float acc = 0.f;
#pragma unroll
  for (int i = 0; i < 4; ++i) {
    float4 v = src[lane + 64 * i];
    acc = fmaf(v.x, v.x, acc);
    acc = fmaf(v.y, v.y, acc);
    acc = fmaf(v.z, v.z, acc);
    acc = fmaf(v.w, v.w, acc);
    ushort4 o;
    o.x = f2bf(v.x); o.y = f2bf(v.y); o.z = f2bf(v.z); o.w = f2bf(v.w);
    const int k4 = (lane + 64 * i) * 4;  // first k of this ushort4
    *(ushort4*)(dstBase + (k4 >> 5) * TILE_SH + (k4 & 31)) = o;
  }
#pragma unroll
  for (int off = 32; off; off >>= 1) acc += __shfl_xor(acc, off, 64);
  if (lane == 0) xn[row] = acc;
}

// ---------------- main: symmetric fused GEMM + triplet reductions ----------------
// grid = 2080 upper-triangle pairs (I<=J).
//
// r10 (K-tiled Hb: contiguous 1KB per gload_lds, full-line L2 requests) was
// the first confirmed win: 122.6 -> 104.4us, MfmaUtil 23->28 (request-path
// serialization was masking everything else). This round grafts the r5
// counted-vmcnt structure (neutral in the OLD regime) onto the K-tiled
// layout: 3 LDS buffers (48KB), stage-ahead 2, one raw s_barrier per K-step,
// s_waitcnt vmcnt(4) in-loop (never 0) — the per-step vmcnt(0) drain of the
// __syncthreads structure is the candidate binding term now that requests
// are dense.
// vmcnt ledger: stage() = 4 gload_lds/wave; before compute(t) only tile
// t+1's 4 loads may be outstanding -> vmcnt(4) proves tile t landed (all
// waves, via the barrier). Regs 84+64 AGPR -> (256,3); LDS 48KB -> 3 blk/CU.
__global__ __launch_bounds__(256, 3) void triplet_main(
    const unsigned short* __restrict__ Hb, const float* __restrict__ xn,
    const int* __restrict__ lab, float* __restrict__ wsMax,
    float* __restrict__ wsM1, float* __restrict__ wsM2) {
  __shared__ __align__(16) unsigned char smem[49152];  // 3 x (8KB A + 8KB B)

  const int tid = threadIdx.x;
  const int wave = tid >> 6;
  const int lane = tid & 63;
  const int quad = lane >> 4;
  const int l15 = lane & 15;
  const int wm = wave & 1;
  const int wn = wave >> 1;

  // XCD-aware swizzle: 8 XCDs, contiguous chunk of 260 pairs per XCD.
  int bid = (int)blockIdx.x;
  bid = (bid & 7) * (NPAIR / 8) + (bid >> 3);

  // decode pair index -> (I, J), I <= J
  int b = bid, I = 0;
  while (b >= NB - I) { b -= NB - I; ++I; }
  const int J = I + b;
  const bool diag = (I == J);

  const int rowBase = I * BM;
  const int colBase = J * BN;

  float maxp[16], mn1[16], mn2[16];
#pragma unroll
  for (int s = 0; s < 16; ++s) { maxp[s] = 0.f; mn1[s] = kInf; mn2[s] = kInf; }

  // staging map: wave stages rows [wave*32 + j*16, +16); lane -> (row, 16B slot)
  // slot is XOR-swizzled within the 64B row via the K-tiled GLOBAL source
  // (within-64B permutation; LDS dest linear as global_load_lds requires).
  const int stR = lane >> 2;                                  // local row 0..15
  const int stRow = wave * 32 + stR;                          // tile row (j adds 16)
  const int stCol = ((lane & 3) ^ ((stR >> 1) & 3)) * 8;      // swizzled short off
  // read-side swizzle: same XOR keyed by the local row (= l15 for frag reads)
  const int swq = quad ^ ((l15 >> 1) & 3);

  f32x4 acc[4][4];
#pragma unroll
  for (int m = 0; m < 4; ++m)
#pragma unroll
    for (int n = 0; n < 4; ++n) acc[m][n] = {0.f, 0.f, 0.f, 0.f};

  // stage K-tile kti into LDS buffer bsel (4 gload_lds per wave: 2 A + 2 B)
  auto stage = [&](int bsel, int kti) {
    unsigned short* As = (unsigned short*)(smem + bsel * 16384);
    unsigned short* Bs = (unsigned short*)(smem + bsel * 16384 + 8192);
    const unsigned short* baseA = Hb + (size_t)(I * 32 + kti) * TILE_SH;
    const unsigned short* baseB = Hb + (size_t)(J * 32 + kti) * TILE_SH;
#pragma unroll
    for (int j = 0; j < 2; ++j) {
      const unsigned short* ga = baseA + (stRow + j * 16) * 32 + stCol;
      __builtin_amdgcn_global_load_lds(
          (const __attribute__((address_space(1))) void*)ga,
          (__attribute__((address_space(3))) void*)&As[(wave * 2 + j) * 512],
          16, 0, 0);
      const unsigned short* gb = baseB + (stRow + j * 16) * 32 + stCol;
      __builtin_amdgcn_global_load_lds(
          (const __attribute__((address_space(1))) void*)gb,
          (__attribute__((address_space(3))) void*)&Bs[(wave * 2 + j) * 512],
          16, 0, 0);
    }
  };

  // prologue: stage tiles 0 and 1 (8 loads/wave in flight; no other vmem in
  // the loop so vmcnt accounting is exact).
  stage(0, 0);
  stage(1, 1);

  int cA = 0, cB = 1, cC = 2;  // cur, next, stage-target
  for (int t = 0; t < NT; ++t) {
    if (t + 1 < NT) {
      asm volatile("s_waitcnt vmcnt(4)" ::: "memory");
    } else {
      asm volatile("s_waitcnt vmcnt(0)" ::: "memory");
    }
    __builtin_amdgcn_s_barrier();
    __builtin_amdgcn_sched_barrier(0);

    if (t + 2 < NT) stage(cC, t + 2);

    const unsigned short* As = (const unsigned short*)(smem + cA * 16384);
    const unsigned short* Bs = (const unsigned short*)(smem + cA * 16384 + 8192);
    bfx8 a[4], bb[4];
#pragma unroll
    for (int m = 0; m < 4; ++m)
      a[m] = *(const bfx8*)&As[(wm * 64 + m * 16 + l15) * BK + swq * 8];
#pragma unroll
    for (int n = 0; n < 4; ++n)
      bb[n] = *(const bfx8*)&Bs[(wn * 64 + n * 16 + l15) * BK + swq * 8];
#pragma unroll
    for (int m = 0; m < 4; ++m)
#pragma unroll
      for (int n = 0; n < 4; ++n)
        acc[m][n] = __builtin_amdgcn_mfma_f32_16x16x32_bf16(a[m], bb[n], acc[m][n], 0, 0, 0);

    const int tmp = cA; cA = cB; cB = cC; cC = tmp;
  }

  // ---- epilogue: dist = xr + xc - 2*G; both-sided masked reductions ----
  // metadata loaded here (kept out of the K-loop so vmcnt accounting is exact)
  int lr[16]; float xr[16];
#pragma unroll
  for (int m = 0; m < 4; ++m)
#pragma unroll
    for (int r = 0; r < 4; ++r) {
      const int row = rowBase + wm * 64 + m * 16 + quad * 4 + r;
      lr[m * 4 + r] = lab[row];
      xr[m * 4 + r] = xn[row];
    }
  int lc[4]; float xc[4];
#pragma unroll
  for (int n = 0; n < 4; ++n) {
    const int col = colBase + wn * 64 + n * 16 + l15;
    lc[n] = lab[col];
    xc[n] = xn[col];
  }
  float tmaxp[4], tmn1[4], tmn2[4];
#pragma unroll
  for (int n = 0; n < 4; ++n) { tmaxp[n] = 0.f; tmn1[n] = kInf; tmn2[n] = kInf; }

  if (!diag) {
#pragma unroll
    for (int m = 0; m < 4; ++m)
#pragma unroll
      for (int n = 0; n < 4; ++n)
#pragma unroll
        for (int r = 0; r < 4; ++r) {
          const int s = m * 4 + r;
          const float d = fmaf(-2.f, acc[m][n][r], xr[s] + xc[n]);
          const bool eq = (lr[s] == lc[n]);
          const float pos = eq ? d : 0.f;
          const float dn = eq ? kInf : d;
          maxp[s] = fmaxf(maxp[s], pos);
          min2_insert(mn1[s], mn2[s], dn);
          tmaxp[n] = fmaxf(tmaxp[n], pos);
          min2_insert(tmn1[n], tmn2[n], dn);
        }
  } else {
#pragma unroll
    for (int m = 0; m < 4; ++m)
#pragma unroll
      for (int n = 0; n < 4; ++n)
#pragma unroll
        for (int r = 0; r < 4; ++r) {
          const int s = m * 4 + r;
          // self-pair only possible on the diagonal tile
          const bool selfp = (wm == wn) && (m == n) && (quad * 4 + r == l15);
          const float d = fmaf(-2.f, acc[m][n][r], xr[s] + xc[n]);
          const bool eq = (lr[s] == lc[n]);
          const float pos = (eq && !selfp) ? d : 0.f;
          const float dn = eq ? kInf : d;  // self is eq -> excluded from negatives
          maxp[s] = fmaxf(maxp[s], pos);
          min2_insert(mn1[s], mn2[s], dn);
        }
  }

  // cross-lane row merge over the 16 column-lanes
#pragma unroll
  for (int off = 1; off < 16; off <<= 1) {
#pragma unroll
    for (int s = 0; s < 16; ++s) {
      const float om = __shfl_xor(maxp[s], off, 64);
      const float o1 = __shfl_xor(mn1[s], off, 64);
      const float o2 = __shfl_xor(mn2[s], off, 64);
      maxp[s] = fmaxf(maxp[s], om);
      min2_merge(mn1[s], mn2[s], o1, o2);
    }
  }

  // ---- LDS scratch phase (reuse buffer 0; barrier orders the last K-tile's
  // readers against the scratch writers) ----
  __syncthreads();
  float* rbuf = (float*)smem;        // [2(wm)][64(local)][3]   = 384 floats
  float* tbm = ((float*)smem) + 384; // [2(wm)][2(wn)][4(q)][4(n)][16(l15)] = 1024 each
  float* tb1 = tbm + 1024;
  float* tb2 = tb1 + 1024;

  if (wn == 1 && l15 == 0) {
#pragma unroll
    for (int m = 0; m < 4; ++m)
#pragma unroll
      for (int r = 0; r < 4; ++r) {
        const int s = m * 4 + r;
        const int local = m * 16 + quad * 4 + r;
        rbuf[(wm * 64 + local) * 3 + 0] = maxp[s];
        rbuf[(wm * 64 + local) * 3 + 1] = mn1[s];
        rbuf[(wm * 64 + local) * 3 + 2] = mn2[s];
      }
  }
#pragma unroll
  for (int n = 0; n < 4; ++n) {
    const int idx = (((wm * 2 + wn) * 4 + quad) * 4 + n) * 16 + l15;
    tbm[idx] = tmaxp[n];
    tb1[idx] = tmn1[n];
    tb2[idx] = tmn2[n];
  }
  __syncthreads();

  // row side: wn==0 waves merge rbuf and write P[I][J]
  if (wn == 0 && l15 == 0) {
#pragma unroll
    for (int m = 0; m < 4; ++m)
#pragma unroll
      for (int r = 0; r < 4; ++r) {
        const int s = m * 4 + r;
        const int local = m * 16 + quad * 4 + r;
        float om = rbuf[(wm * 64 + local) * 3 + 0];
        float o1 = rbuf[(wm * 64 + local) * 3 + 1];
        float o2 = rbuf[(wm * 64 + local) * 3 + 2];
        const float M = fmaxf(maxp[s], om);
        float a1 = mn1[s], a2 = mn2[s];
        min2_merge(a1, a2, o1, o2);
        const size_t p = ((size_t)(I * NB + J)) * 128 + wm * 64 + local;
        wsMax[p] = M;
        wsM1[p] = a1;
        wsM2[p] = a2;
      }
  }
  // transposed side: wm==0 waves merge tbuf over {wm2, quad} and write P[J][I]
  if (wm == 0 && !diag) {
    const int tn = lane >> 4;
    const int tl = lane & 15;
    float M = 0.f, a1 = kInf, a2 = kInf;
#pragma unroll
    for (int wm2 = 0; wm2 < 2; ++wm2)
#pragma unroll
      for (int q = 0; q < 4; ++q) {
        const int idx = (((wm2 * 2 + wn) * 4 + q) * 4 + tn) * 16 + tl;
        M = fmaxf(M, tbm[idx]);
        min2_merge(a1, a2, tb1[idx], tb2[idx]);
      }
    const size_t p = ((size_t)(J * NB + I)) * 128 + wn * 64 + lane;
    wsMax[p] = M;
    wsM1[p] = a1;
    wsM2[p] = a2;
  }
}

// ---------------- merge: per-row over 64 col-block partials -> block sums ----
// 256 threads: row = tid&127, half = tid>>7 covers 32 of the 64 bj each;
// halves merged through LDS, loss computed on half 0.
__global__ __launch_bounds__(256) void merge_kernel(
    const float* __restrict__ wsMax, const float* __restrict__ wsM1,
    const float* __restrict__ wsM2, float* __restrict__ bsum,
    float* __restrict__ bcnt) {
  const int r = threadIdx.x & 127;
  const int h = threadIdx.x >> 7;
  const int bi = blockIdx.x;
  float mp = 0.f, m1 = kInf, m2 = kInf;
#pragma unroll 8
  for (int bj = h * 32; bj < h * 32 + 32; ++bj) {
    const size_t p = ((size_t)(bi * NB + bj)) * 128 + r;
    mp = fmaxf(mp, wsMax[p]);
    min2_merge(m1, m2, wsM1[p], wsM2[p]);
  }
  __shared__ float hmax[128], hm1[128], hm2[128];
  if (h == 1) { hmax[r] = mp; hm1[r] = m1; hm2[r] = m2; }
  __syncthreads();
  float ls = 0.f, lc = 0.f;
  if (h == 0) {
    mp = fmaxf(mp, hmax[r]);
    min2_merge(m1, m2, hm1[r], hm2[r]);
    const float loss = fmaxf(mp - m2 + kAlpha, 0.f);
    ls = (loss > kEps) ? loss : 0.f;
    lc = (loss > kEps) ? 1.f : 0.f;
  }
#pragma unroll
  for (int off = 32; off; off >>= 1) {
    ls += __shfl_down(ls, off, 64);
    lc += __shfl_down(lc, off, 64);
  }
  __shared__ float ss[2], sc[2];
  if (h == 0 && (threadIdx.x & 63) == 0) {
    ss[threadIdx.x >> 6] = ls;
    sc[threadIdx.x >> 6] = lc;
  }
  __syncthreads();
  if (threadIdx.x == 0) {
    bsum[bi] = ss[0] + ss[1];
    bcnt[bi] = sc[0] + sc[1];
  }
}

// ---------------- final: reduce 64 block sums, divide ----------------
__global__ __launch_bounds__(64) void final_kernel(const float* __restrict__ bsum,
                                                   const float* __restrict__ bcnt,
                                                   float* __restrict__ out) {
  float s = bsum[threadIdx.x];
  float c = bcnt[threadIdx.x];
#pragma unroll
  for (int off = 32; off; off >>= 1) {
    s += __shfl_down(s, off, 64);
    c += __shfl_down(c, off, 64);
  }
  if (threadIdx.x == 0) out[0] = s / c;
}

// ---------------- launch ----------------
extern "C" void kernel_launch(void* const* d_in, const int* in_sizes, int n_in,
                              void* d_out, int out_size, void* d_ws, size_t ws_size,
                              hipStream_t stream) {
  (void)in_sizes; (void)n_in; (void)out_size; (void)ws_size;
  const float* H = (const float*)d_in[0];
  const int* lab = (const int*)d_in[1];
  float* out = (float*)d_out;

  char* ws = (char*)d_ws;
  unsigned short* Hb = (unsigned short*)ws;                              // 16 MB (K-tiled)
  float* xn = (float*)(ws + (size_t)Nn * Dd * sizeof(unsigned short));   // 32 KB
  float* wsMax = xn + Nn;                 // 64*64*128 = 512K floats = 2 MB
  float* wsM1 = wsMax + NB * NB * 128;
  float* wsM2 = wsM1 + NB * NB * 128;
  float* bsum = wsM2 + NB * NB * 128;     // 64 floats
  float* bcnt = bsum + NB;

  prep_kernel<<<Nn / 4, 256, 0, stream>>>(H, Hb, xn);
  triplet_main<<<NPAIR, 256, 0, stream>>>(Hb, xn, lab, wsMax, wsM1, wsM2);
  merge_kernel<<<NB, 256, 0, stream>>>(wsMax, wsM1, wsM2, bsum, bcnt);
  final_kernel<<<1, 64, 0, stream>>>(bsum, bcnt, out);
}

// Round 12
// 177.723 us; speedup vs baseline: 1.9132x; 1.0304x over previous
//
#include <hip/hip_runtime.h>
#include <hip/hip_bf16.h>
#include <stdint.h>

// ---------------- constants ----------------
constexpr int Nn = 8192;
constexpr int Dd = 1024;
constexpr float kAlpha = 0.1f;
constexpr float kEps = 1e-7f;
constexpr float kInf = 3.0e38f;

constexpr int BM = 128, BN = 128, BK = 32;
constexpr int NB = Nn / BM;               // 64 row/col blocks
constexpr int NPAIR = NB * (NB + 1) / 2;  // 2080 upper-triangle tile pairs
constexpr int NT = Dd / BK;               // 32 K-steps

// Hb is stored K-TILED: [rowBlk 64][kt 32][row 128][k 32] — each 128x32 tile
// is a contiguous 8 KB blob (4096 shorts). Offset(row,k) =
//   ((row>>7)*32 + (k>>5))*4096 + (row&127)*32 + (k&31)
constexpr int TILE_SH = 4096;             // shorts per 8 KB tile

using bfx8 = __attribute__((ext_vector_type(8))) __bf16;   // MFMA A/B frag (4 VGPRs)
using f32x4 = __attribute__((ext_vector_type(4))) float;   // MFMA C/D frag

__device__ __forceinline__ unsigned short f2bf(float f) {
  union { float f; unsigned int u; } v; v.f = f;
  unsigned int u = v.u;
  u = u + 0x7fffu + ((u >> 16) & 1u);  // RNE
  return (unsigned short)(u >> 16);
}

__device__ __forceinline__ void min2_insert(float& m1, float& m2, float x) {
  const float lo = fminf(m1, x);
  const float hi = fmaxf(m1, x);
  m1 = lo;
  m2 = fminf(m2, hi);
}

__device__ __forceinline__ void min2_merge(float& m1, float& m2, float o1, float o2) {
  m2 = fminf(fminf(m2, o2), fmaxf(m1, o1));
  m1 = fminf(m1, o1);
}

// ---------------- prep: fp32 -> bf16 (K-tiled layout) + row sq-norms --------
__global__ __launch_bounds__(256) void prep_kernel(const float* __restrict__ H,
                                                   unsigned short* __restrict__ Hb,
                                                   float* __restrict__ xn) {
  const int wave = threadIdx.x >> 6;
  const int lane = threadIdx.x & 63;
  const int row = blockIdx.x * 4 + wave;
  const float4* src = (const float4*)(H + (size_t)row * Dd);
  // K-tiled destination: tile (row>>7, k>>5), element (row&127, k&31)
  unsigned short* dstBase =
      Hb + ((size_t)(row >> 7) * 32) * TILE_SH + (row & 127) * 32;
  float acc = 0.f;
#pragma unroll
  for (int i = 0; i < 4; ++i) {
    float4 v = src[lane + 64 * i];
    acc = fmaf(v.x, v.x, acc);
    acc = fmaf(v.y, v.y, acc);
    acc = fmaf(v.z, v.z, acc);
    acc = fmaf(v.w, v.w, acc);
    ushort4 o;
    o.x = f2bf(v.x); o.y = f2bf(v.y); o.z = f2bf(v.z); o.w = f2bf(v.w);
    const int k4 = (lane + 64 * i) * 4;  // first k of this ushort4
    *(ushort4*)(dstBase + (k4 >> 5) * TILE_SH + (k4 & 31)) = o;
  }
#pragma unroll
  for (int off = 32; off; off >>= 1) acc += __shfl_xor(acc, off, 64);
  if (lane == 0) xn[row] = acc;
}

// ---------------- main: symmetric fused GEMM + triplet reductions ----------------
// grid = 2080 upper-triangle pairs (I<=J).
//
// Base = r10 (K-tiled Hb, 2-buffer prefetch + syncthreads loop; 104.4us,
// first confirmed win). This round: unlock 4 blocks/CU. The r10 footprint was
// 84 arch VGPR + 64 AGPR = 148/wave (3 waves/SIMD max); the 84 peak is the
// EPILOGUE (row stats 48 + col stats 12 + metadata 24 all live). Restructure:
// process row stats PER-M (4 rows at a time -> shuffle-merge -> LDS rbuf,
// both wn halves write; 128-thread final merge), metadata loaded per-m.
// Peak drops to ~114-118 total -> __launch_bounds__(256,4) legal, LDS
// 4 x 32KB = 128KB, 16 waves/CU: SIMD issue ports (VALU 32% + MFMA 27% ~ 59%
// at 3 waves/SIMD) get a 4th wave to pack.
__global__ __launch_bounds__(256, 4) void triplet_main(
    const unsigned short* __restrict__ Hb, const float* __restrict__ xn,
    const int* __restrict__ lab, float* __restrict__ wsMax,
    float* __restrict__ wsM1, float* __restrict__ wsM2) {
  __shared__ __align__(16) unsigned char smem[32768];  // 2 x (8KB A + 8KB B)

  const int tid = threadIdx.x;
  const int wave = tid >> 6;
  const int lane = tid & 63;
  const int quad = lane >> 4;
  const int l15 = lane & 15;
  const int wm = wave & 1;
  const int wn = wave >> 1;

  // XCD-aware swizzle: 8 XCDs, contiguous chunk of 260 pairs per XCD.
  int bid = (int)blockIdx.x;
  bid = (bid & 7) * (NPAIR / 8) + (bid >> 3);

  // decode pair index -> (I, J), I <= J
  int b = bid, I = 0;
  while (b >= NB - I) { b -= NB - I; ++I; }
  const int J = I + b;
  const bool diag = (I == J);

  const int rowBase = I * BM;
  const int colBase = J * BN;

  // staging map: wave stages rows [wave*32 + j*16, +16); lane -> (row, 16B slot)
  // slot is XOR-swizzled within the 64B row via the K-tiled GLOBAL source
  // (within-64B permutation; LDS dest linear as global_load_lds requires).
  const int stR = lane >> 2;                                  // local row 0..15
  const int stRow = wave * 32 + stR;                          // tile row (j adds 16)
  const int stCol = ((lane & 3) ^ ((stR >> 1) & 3)) * 8;      // swizzled short off
  // read-side swizzle: same XOR keyed by the local row (= l15 for frag reads)
  const int swq = quad ^ ((l15 >> 1) & 3);

  f32x4 acc[4][4];
#pragma unroll
  for (int m = 0; m < 4; ++m)
#pragma unroll
    for (int n = 0; n < 4; ++n) acc[m][n] = {0.f, 0.f, 0.f, 0.f};

  auto stage = [&](int bsel, int kti) {  // kti = K-tile index (k/32)
    unsigned short* As = (unsigned short*)(smem + bsel * 16384);
    unsigned short* Bs = (unsigned short*)(smem + bsel * 16384 + 8192);
    const unsigned short* baseA = Hb + (size_t)(I * 32 + kti) * TILE_SH;
    const unsigned short* baseB = Hb + (size_t)(J * 32 + kti) * TILE_SH;
#pragma unroll
    for (int j = 0; j < 2; ++j) {
      const unsigned short* ga = baseA + (stRow + j * 16) * 32 + stCol;
      __builtin_amdgcn_global_load_lds(
          (const __attribute__((address_space(1))) void*)ga,
          (__attribute__((address_space(3))) void*)&As[(wave * 2 + j) * 512],
          16, 0, 0);
      const unsigned short* gb = baseB + (stRow + j * 16) * 32 + stCol;
      __builtin_amdgcn_global_load_lds(
          (const __attribute__((address_space(1))) void*)gb,
          (__attribute__((address_space(3))) void*)&Bs[(wave * 2 + j) * 512],
          16, 0, 0);
    }
  };

  // prologue: stage tile 0 into buffer 0, drain, then pipeline.
  stage(0, 0);
  __syncthreads();  // drains vmcnt (global_load_lds) + lgkm

  int cur = 0;
  for (int kti = 0; kti < NT; ++kti) {
    if (kti + 1 < NT) stage(cur ^ 1, kti + 1);  // prefetch next (issue only)

    const unsigned short* As = (const unsigned short*)(smem + cur * 16384);
    const unsigned short* Bs = (const unsigned short*)(smem + cur * 16384 + 8192);
    bfx8 a[4], bb[4];
#pragma unroll
    for (int m = 0; m < 4; ++m)
      a[m] = *(const bfx8*)&As[(wm * 64 + m * 16 + l15) * BK + swq * 8];
#pragma unroll
    for (int n = 0; n < 4; ++n)
      bb[n] = *(const bfx8*)&Bs[(wn * 64 + n * 16 + l15) * BK + swq * 8];
#pragma unroll
    for (int m = 0; m < 4; ++m)
#pragma unroll
      for (int n = 0; n < 4; ++n)
        acc[m][n] = __builtin_amdgcn_mfma_f32_16x16x32_bf16(a[m], bb[n], acc[m][n], 0, 0, 0);

    __syncthreads();  // one drain+barrier per K-step; prefetch had compute cover
    cur ^= 1;
  }

  // ---- epilogue: dist = xr + xc - 2*G; both-sided masked reductions ----
  // LDS scratch (staging buffers are free after the loop's final barrier):
  // rbuf[2(wn)][128(row)][3] = 768 floats; tbm/tb1/tb2 1024 floats each.
  float* rbuf = (float*)smem;
  float* tbm = ((float*)smem) + 768;
  float* tb1 = tbm + 1024;
  float* tb2 = tb1 + 1024;

  int lc[4]; float xc[4];
#pragma unroll
  for (int n = 0; n < 4; ++n) {
    const int col = colBase + wn * 64 + n * 16 + l15;
    lc[n] = lab[col];
    xc[n] = xn[col];
  }
  float tmaxp[4], tmn1[4], tmn2[4];
#pragma unroll
  for (int n = 0; n < 4; ++n) { tmaxp[n] = 0.f; tmn1[n] = kInf; tmn2[n] = kInf; }

  // per-m: compute 4 rows' stats, shuffle-merge over 16 col-lanes, park in LDS
#pragma unroll
  for (int m = 0; m < 4; ++m) {
    int lr4[4]; float xr4[4];
#pragma unroll
    for (int r = 0; r < 4; ++r) {
      const int row = rowBase + wm * 64 + m * 16 + quad * 4 + r;
      lr4[r] = lab[row];
      xr4[r] = xn[row];
    }
    float rmax[4], r1v[4], r2v[4];
#pragma unroll
    for (int r = 0; r < 4; ++r) { rmax[r] = 0.f; r1v[r] = kInf; r2v[r] = kInf; }

    if (!diag) {
#pragma unroll
      for (int n = 0; n < 4; ++n)
#pragma unroll
        for (int r = 0; r < 4; ++r) {
          const float d = fmaf(-2.f, acc[m][n][r], xr4[r] + xc[n]);
          const bool eq = (lr4[r] == lc[n]);
          const float pos = eq ? d : 0.f;
          const float dn = eq ? kInf : d;
          rmax[r] = fmaxf(rmax[r], pos);
          min2_insert(r1v[r], r2v[r], dn);
          tmaxp[n] = fmaxf(tmaxp[n], pos);
          min2_insert(tmn1[n], tmn2[n], dn);
        }
    } else {
#pragma unroll
      for (int n = 0; n < 4; ++n)
#pragma unroll
        for (int r = 0; r < 4; ++r) {
          // self-pair only possible on the diagonal tile
          const bool selfp = (wm == wn) && (m == n) && (quad * 4 + r == l15);
          const float d = fmaf(-2.f, acc[m][n][r], xr4[r] + xc[n]);
          const bool eq = (lr4[r] == lc[n]);
          const float pos = (eq && !selfp) ? d : 0.f;
          const float dn = eq ? kInf : d;  // self is eq -> excluded from negatives
          rmax[r] = fmaxf(rmax[r], pos);
          min2_insert(r1v[r], r2v[r], dn);
        }
    }

    // merge over the 16 column-lanes (lane bits 0..3)
#pragma unroll
    for (int off = 1; off < 16; off <<= 1) {
#pragma unroll
      for (int r = 0; r < 4; ++r) {
        const float om = __shfl_xor(rmax[r], off, 64);
        const float o1 = __shfl_xor(r1v[r], off, 64);
        const float o2 = __shfl_xor(r2v[r], off, 64);
        rmax[r] = fmaxf(rmax[r], om);
        min2_merge(r1v[r], r2v[r], o1, o2);
      }
    }
    if (l15 == 0) {
#pragma unroll
      for (int r = 0; r < 4; ++r) {
        const int row = wm * 64 + m * 16 + quad * 4 + r;
        rbuf[(wn * 128 + row) * 3 + 0] = rmax[r];
        rbuf[(wn * 128 + row) * 3 + 1] = r1v[r];
        rbuf[(wn * 128 + row) * 3 + 2] = r2v[r];
      }
    }
  }

  // col-side partials to LDS (proven r1 path; writes harmless on diag)
#pragma unroll
  for (int n = 0; n < 4; ++n) {
    const int idx = (((wm * 2 + wn) * 4 + quad) * 4 + n) * 16 + l15;
    tbm[idx] = tmaxp[n];
    tb1[idx] = tmn1[n];
    tb2[idx] = tmn2[n];
  }
  __syncthreads();

  // row side: 128 threads merge the two wn halves and write P[I][J]
  if (tid < 128) {
    const int row = tid;
    float M = fmaxf(rbuf[row * 3 + 0], rbuf[(128 + row) * 3 + 0]);
    float a1 = rbuf[row * 3 + 1], a2 = rbuf[row * 3 + 2];
    min2_merge(a1, a2, rbuf[(128 + row) * 3 + 1], rbuf[(128 + row) * 3 + 2]);
    const size_t p = ((size_t)(I * NB + J)) * 128 + row;
    wsMax[p] = M;
    wsM1[p] = a1;
    wsM2[p] = a2;
  }
  // transposed side: wm==0 waves merge tbuf over {wm2, quad} and write P[J][I]
  if (wm == 0 && !diag) {
    const int tn = lane >> 4;
    const int tl = lane & 15;
    float M = 0.f, a1 = kInf, a2 = kInf;
#pragma unroll
    for (int wm2 = 0; wm2 < 2; ++wm2)
#pragma unroll
      for (int q = 0; q < 4; ++q) {
        const int idx = (((wm2 * 2 + wn) * 4 + q) * 4 + tn) * 16 + tl;
        M = fmaxf(M, tbm[idx]);
        min2_merge(a1, a2, tb1[idx], tb2[idx]);
      }
    const size_t p = ((size_t)(J * NB + I)) * 128 + wn * 64 + lane;
    wsMax[p] = M;
    wsM1[p] = a1;
    wsM2[p] = a2;
  }
}

// ---------------- merge: per-row over 64 col-block partials -> block sums ----
// 256 threads: row = tid&127, half = tid>>7 covers 32 of the 64 bj each;
// halves merged through LDS, loss computed on half 0.
__global__ __launch_bounds__(256) void merge_kernel(
    const float* __restrict__ wsMax, const float* __restrict__ wsM1,
    const float* __restrict__ wsM2, float* __restrict__ bsum,
    float* __restrict__ bcnt) {
  const int r = threadIdx.x & 127;
  const int h = threadIdx.x >> 7;
  const int bi = blockIdx.x;
  float mp = 0.f, m1 = kInf, m2 = kInf;
#pragma unroll 8
  for (int bj = h * 32; bj < h * 32 + 32; ++bj) {
    const size_t p = ((size_t)(bi * NB + bj)) * 128 + r;
    mp = fmaxf(mp, wsMax[p]);
    min2_merge(m1, m2, wsM1[p], wsM2[p]);
  }
  __shared__ float hmax[128], hm1[128], hm2[128];
  if (h == 1) { hmax[r] = mp; hm1[r] = m1; hm2[r] = m2; }
  __syncthreads();
  float ls = 0.f, lc = 0.f;
  if (h == 0) {
    mp = fmaxf(mp, hmax[r]);
    min2_merge(m1, m2, hm1[r], hm2[r]);
    const float loss = fmaxf(mp - m2 + kAlpha, 0.f);
    ls = (loss > kEps) ? loss : 0.f;
    lc = (loss > kEps) ? 1.f : 0.f;
  }
#pragma unroll
  for (int off = 32; off; off >>= 1) {
    ls += __shfl_down(ls, off, 64);
    lc += __shfl_down(lc, off, 64);
  }
  __shared__ float ss[2], sc[2];
  if (h == 0 && (threadIdx.x & 63) == 0) {
    ss[threadIdx.x >> 6] = ls;
    sc[threadIdx.x >> 6] = lc;
  }
  __syncthreads();
  if (threadIdx.x == 0) {
    bsum[bi] = ss[0] + ss[1];
    bcnt[bi] = sc[0] + sc[1];
  }
}

// ---------------- final: reduce 64 block sums, divide ----------------
__global__ __launch_bounds__(64) void final_kernel(const float* __restrict__ bsum,
                                                   const float* __restrict__ bcnt,
                                                   float* __restrict__ out) {
  float s = bsum[threadIdx.x];
  float c = bcnt[threadIdx.x];
#pragma unroll
  for (int off = 32; off; off >>= 1) {
    s += __shfl_down(s, off, 64);
    c += __shfl_down(c, off, 64);
  }
  if (threadIdx.x == 0) out[0] = s / c;
}

// ---------------- launch ----------------
extern "C" void kernel_launch(void* const* d_in, const int* in_sizes, int n_in,
                              void* d_out, int out_size, void* d_ws, size_t ws_size,
                              hipStream_t stream) {
  (void)in_sizes; (void)n_in; (void)out_size; (void)ws_size;
  const float* H = (const float*)d_in[0];
  const int* lab = (const int*)d_in[1];
  float* out = (float*)d_out;

  char* ws = (char*)d_ws;
  unsigned short* Hb = (unsigned short*)ws;                              // 16 MB (K-tiled)
  float* xn = (float*)(ws + (size_t)Nn * Dd * sizeof(unsigned short));   // 32 KB
  float* wsMax = xn + Nn;                 // 64*64*128 = 512K floats = 2 MB
  float* wsM1 = wsMax + NB * NB * 128;
  float* wsM2 = wsM1 + NB * NB * 128;
  float* bsum = wsM2 + NB * NB * 128;     // 64 floats
  float* bcnt = bsum + NB;

  prep_kernel<<<Nn / 4, 256, 0, stream>>>(H, Hb, xn);
  triplet_main<<<NPAIR, 256, 0, stream>>>(Hb, xn, lab, wsMax, wsM1, wsM2);
  merge_kernel<<<NB, 256, 0, stream>>>(wsMax, wsM1, wsM2, bsum, bcnt);
  final_kernel<<<1, 64, 0, stream>>>(bsum, bcnt, out);
}